// Round 6
// baseline (209.187 us; speedup 1.0000x reference)
//
#include <hip/hip_runtime.h>
#include <math.h>

#define K 512
#define K4 128              // K/4
#define NQ 4
#define NL 6
#define NC 10

// DPP quad_perm cross-lane xor (pure VALU, no DS pipe)
__device__ __forceinline__ float dpp_xor1(float v) {
    return __int_as_float(__builtin_amdgcn_mov_dpp(__float_as_int(v), 0xB1, 0xF, 0xF, true));
}
__device__ __forceinline__ float dpp_xor2(float v) {
    return __int_as_float(__builtin_amdgcn_mov_dpp(__float_as_int(v), 0x4E, 0xF, 0xF, true));
}

// ============== Fused kernel: GEMV + tanh + VQC sim + post-net ==============
// Phase 1 (all 256 thr): wave-per-row GEMV, W_pre in regs, DPP fold, depth-2
//   row-pair pipeline; partials -> LDS; tail sums + tanh -> angles in LDS.
// Phase 2 (64 thr): per-row 16-amp register sim, gates via ds_read_b128,
//   post-net 4->10, direct store. One dispatch, d_ws unused.
#define A_BLOCK 256
#define A_WAVES 4
#define A_ROWS_PER_WAVE 16
#define A_ROWS_PER_BLOCK 64   // A_WAVES * A_ROWS_PER_WAVE
#define A_PAIRS 8             // 16 rows as 8 pairs
#define PART_STRIDE 68        // 64 partials + pad, multiple of 4 for b128 align

__global__ __launch_bounds__(A_BLOCK, 4) void vqc_fused_kernel(
    const float* __restrict__ x,
    const float* __restrict__ W_pre,
    const float* __restrict__ b_pre,
    const float* __restrict__ q_weights,
    const float* __restrict__ W_post,
    const float* __restrict__ b_post,
    float* __restrict__ out)
{
    __shared__ float part[A_ROWS_PER_BLOCK * PART_STRIDE];  // 17.4 KB
    __shared__ float angles_s[A_ROWS_PER_BLOCK][NQ];        // 1 KB
    __shared__ float4 gates4[NL * NQ][2];  // [g][0]=(g00r,g00i,g01r,g01i) [1]=(g10..)
    __shared__ float Wpost_s[NC * NQ];
    __shared__ float bpost_s[NC];

    const int tid  = threadIdx.x;
    const int wave = tid >> 6;
    const int lane = tid & 63;

    // ---- batch-invariant small-param staging (concurrent with phase 1) ----
    if (tid < NL * NQ) {
        const int l = tid >> 2, w = tid & 3;
        const float phi = q_weights[l * 12 + w * 3 + 0];
        const float th  = q_weights[l * 12 + w * 3 + 1];
        const float om  = q_weights[l * 12 + w * 3 + 2];
        const float c  = cosf(0.5f * th), s = sinf(0.5f * th);
        const float hp = 0.5f * (phi + om), hm = 0.5f * (phi - om);
        const float epr = cosf(hp), epi = -sinf(hp);   // exp(-i(phi+om)/2)
        const float emr = cosf(hm), emi = -sinf(hm);   // exp(-i(phi-om)/2)
        gates4[tid][0] = make_float4( epr * c,  epi * c, -emr * s,  emi * s);
        gates4[tid][1] = make_float4( emr * s,  emi * s,  epr * c, -epi * c);
    }
    if (tid >= 64 && tid < 64 + NC * NQ) Wpost_s[tid - 64] = W_post[tid - 64];
    if (tid >= 104 && tid < 104 + NC)    bpost_s[tid - 104] = b_post[tid - 104];

    // ---- phase 1: pre-net GEMV ----
    const float4* x4 = (const float4*)x;
    const float4* W4 = (const float4*)W_pre;
    // lane owns k-slices {lane, 64+lane} (float4 units); W regs live across rows
    const float4 w0a = W4[0 * K4 + lane], w0b = W4[0 * K4 + 64 + lane];
    const float4 w1a = W4[1 * K4 + lane], w1b = W4[1 * K4 + 64 + lane];
    const float4 w2a = W4[2 * K4 + lane], w2b = W4[2 * K4 + 64 + lane];
    const float4 w3a = W4[3 * K4 + lane], w3b = W4[3 * K4 + 64 + lane];

    const int rowBase = blockIdx.x * A_ROWS_PER_BLOCK + wave * A_ROWS_PER_WAVE;
    const int partOff = (lane & 3) * 16 + (lane >> 2);  // (wire, seg) slot

    float4 bufa[2][2], bufb[2][2];   // [parity][row-in-pair]
    {
        const float4* r0 = x4 + (size_t)(rowBase + 0) * K4;
        const float4* r1 = x4 + (size_t)(rowBase + 1) * K4;
        bufa[0][0] = r0[lane]; bufb[0][0] = r0[64 + lane];
        bufa[0][1] = r1[lane]; bufb[0][1] = r1[64 + lane];
    }

    #pragma unroll
    for (int p = 0; p < A_PAIRS; ++p) {
        const int cp = p & 1, np = cp ^ 1;
        if (p + 1 < A_PAIRS) {      // prefetch next pair (4KB/wave in flight)
            const float4* r0 = x4 + (size_t)(rowBase + 2 * p + 2) * K4;
            const float4* r1 = x4 + (size_t)(rowBase + 2 * p + 3) * K4;
            bufa[np][0] = r0[lane]; bufb[np][0] = r0[64 + lane];
            bufa[np][1] = r1[lane]; bufb[np][1] = r1[64 + lane];
        }
        #pragma unroll
        for (int rr = 0; rr < 2; ++rr) {
            const float4 xa = bufa[cp][rr];
            const float4 xb = bufb[cp][rr];
            float acc0 = xa.x * w0a.x + xa.y * w0a.y + xa.z * w0a.z + xa.w * w0a.w
                       + xb.x * w0b.x + xb.y * w0b.y + xb.z * w0b.z + xb.w * w0b.w;
            float acc1 = xa.x * w1a.x + xa.y * w1a.y + xa.z * w1a.z + xa.w * w1a.w
                       + xb.x * w1b.x + xb.y * w1b.y + xb.z * w1b.z + xb.w * w1b.w;
            float acc2 = xa.x * w2a.x + xa.y * w2a.y + xa.z * w2a.z + xa.w * w2a.w
                       + xb.x * w2b.x + xb.y * w2b.y + xb.z * w2b.z + xb.w * w2b.w;
            float acc3 = xa.x * w3a.x + xa.y * w3a.y + xa.z * w3a.z + xa.w * w3a.w
                       + xb.x * w3b.x + xb.y * w3b.y + xb.z * w3b.z + xb.w * w3b.w;

            // fold 4 accs -> 1 per lane with quad-local DPP (pure VALU)
            const bool b0 = (lane & 1);
            float pA = b0 ? acc1 : acc0;
            float qA = b0 ? acc0 : acc1;
            pA += dpp_xor1(qA);
            float pB = b0 ? acc3 : acc2;
            float qB = b0 ? acc2 : acc3;
            pB += dpp_xor1(qB);
            const bool b1 = (lane & 2);
            float pv = b1 ? pB : pA;
            float qv = b1 ? pA : pB;
            pv += dpp_xor2(qv);
            // lane holds partial for wire (lane&3), segment (lane>>2)

            part[(wave * A_ROWS_PER_WAVE + 2 * p + rr) * PART_STRIDE + partOff] = pv;
        }
    }
    __syncthreads();

    // ---- tail: one thread per (row, wire), sum 16 segment partials ----
    {
        const int row  = tid >> 2;          // 0..63
        const int wire = tid & 3;
        const float4* seg4 = (const float4*)&part[row * PART_STRIDE + wire * 16];
        const float4 s0 = seg4[0], s1 = seg4[1], s2 = seg4[2], s3 = seg4[3];
        const float s = ((s0.x + s0.y) + (s0.z + s0.w))
                      + ((s1.x + s1.y) + (s1.z + s1.w))
                      + ((s2.x + s2.y) + (s2.z + s2.w))
                      + ((s3.x + s3.y) + (s3.z + s3.w));
        const float z = s + b_pre[wire];
        // tanh(z) = 1 - 2/(exp(2z)+1), exp via hardware v_exp_f32
        const float e = __expf(2.f * z);
        const float th = 1.f - 2.f / (e + 1.f);
        angles_s[row][wire] = th * 3.14159265358979323846f;
    }
    __syncthreads();

    // ---- phase 2: per-row register sim + post-net (64 lanes) ----
    if (tid < A_ROWS_PER_BLOCK) {
        const int rl = tid;
        const int r  = blockIdx.x * A_ROWS_PER_BLOCK + rl;
        const float a0 = angles_s[rl][0], a1 = angles_s[rl][1];
        const float a2 = angles_s[rl][2], a3 = angles_s[rl][3];
        float c0, s0, c1, s1, c2, s2, c3, s3;
        __sincosf(0.5f * a0, &s0, &c0);
        __sincosf(0.5f * a1, &s1, &c1);
        __sincosf(0.5f * a2, &s2, &c2);
        __sincosf(0.5f * a3, &s3, &c3);

        // |psi> = RY(a0)|0> x RY(a1)|0> x RY(a2)|0> x RY(a3)|0>  (real)
        float ar[16], ai[16];
        #pragma unroll
        for (int i = 0; i < 16; ++i) {
            ar[i] = ((i & 8) ? s0 : c0) * ((i & 4) ? s1 : c1)
                  * ((i & 2) ? s2 : c2) * ((i & 1) ? s3 : c3);
            ai[i] = 0.f;
        }

        #pragma unroll
        for (int l = 0; l < NL; ++l) {
            #pragma unroll
            for (int w = 0; w < NQ; ++w) {
                const float4 G0 = gates4[l * 4 + w][0];  // ds_read_b128 broadcast
                const float4 G1 = gates4[l * 4 + w][1];
                const float g00r = G0.x, g00i = G0.y, g01r = G0.z, g01i = G0.w;
                const float g10r = G1.x, g10i = G1.y, g11r = G1.z, g11i = G1.w;
                const int m = 8 >> w;
                #pragma unroll
                for (int i0 = 0; i0 < 16; ++i0) {
                    if (i0 & m) continue;
                    const int i1 = i0 | m;
                    const float A0r = ar[i0], A0i = ai[i0];
                    const float A1r = ar[i1], A1i = ai[i1];
                    ar[i0] = g00r * A0r - g00i * A0i + g01r * A1r - g01i * A1i;
                    ai[i0] = g00r * A0i + g00i * A0r + g01r * A1i + g01i * A1r;
                    ar[i1] = g10r * A0r - g10i * A0i + g11r * A1r - g11i * A1i;
                    ai[i1] = g10r * A0i + g10i * A0r + g11r * A1i + g11i * A1r;
                }
            }
            const int rshift = l % 3 + 1;
            // CNOT ring: pure compile-time register permutation
            #pragma unroll
            for (int w = 0; w < NQ; ++w) {
                const int cm = 8 >> w;
                const int tm = 8 >> ((w + rshift) & 3);
                #pragma unroll
                for (int i = 0; i < 16; ++i) {
                    if ((i & cm) && !(i & tm)) {
                        const int ii = i | tm;
                        float t;
                        t = ar[i]; ar[i] = ar[ii]; ar[ii] = t;
                        t = ai[i]; ai[i] = ai[ii]; ai[ii] = t;
                    }
                }
            }
        }

        // Z expectations per wire
        float e0 = 0.f, e1 = 0.f, e2 = 0.f, e3 = 0.f;
        #pragma unroll
        for (int i = 0; i < 16; ++i) {
            const float pr = ar[i] * ar[i] + ai[i] * ai[i];
            e0 += (i & 8) ? -pr : pr;
            e1 += (i & 4) ? -pr : pr;
            e2 += (i & 2) ? -pr : pr;
            e3 += (i & 1) ? -pr : pr;
        }

        // post-net 4 -> 10, stored as 5 aligned float2 (row offset 40B, 8B-aligned)
        float o[NC];
        #pragma unroll
        for (int c = 0; c < NC; ++c) {
            o[c] = bpost_s[c]
                 + Wpost_s[c * 4 + 0] * e0 + Wpost_s[c * 4 + 1] * e1
                 + Wpost_s[c * 4 + 2] * e2 + Wpost_s[c * 4 + 3] * e3;
        }
        float2* orow2 = (float2*)(out + (size_t)r * NC);
        #pragma unroll
        for (int c = 0; c < 5; ++c)
            orow2[c] = make_float2(o[2 * c], o[2 * c + 1]);
    }
}

extern "C" void kernel_launch(void* const* d_in, const int* in_sizes, int n_in,
                              void* d_out, int out_size, void* d_ws, size_t ws_size,
                              hipStream_t stream) {
    const float* x         = (const float*)d_in[0];
    const float* W_pre     = (const float*)d_in[1];
    const float* b_pre     = (const float*)d_in[2];
    const float* q_weights = (const float*)d_in[3];
    const float* W_post    = (const float*)d_in[4];
    const float* b_post    = (const float*)d_in[5];
    float* out = (float*)d_out;

    const int B = in_sizes[0] / K;              // 65536
    dim3 grid(B / A_ROWS_PER_BLOCK);            // 1024 blocks -> 4/CU, 1 round
    vqc_fused_kernel<<<grid, A_BLOCK, 0, stream>>>(x, W_pre, b_pre, q_weights,
                                                   W_post, b_post, out);
}